// Round 4
// baseline (905.502 us; speedup 1.0000x reference)
//
#include <hip/hip_runtime.h>
#include <stdint.h>

// ---------------- problem constants ----------------
#define NTOK   16384      // B*S
#define HDIM   1024
#define IDIM   2048
#define NEXP   8
#define NASG   (NTOK*2)   // top-2 assignments
#define RBLK   512        // router grid blocks (2 per CU)

typedef __bf16 bf16x8 __attribute__((ext_vector_type(8)));
typedef float  f32x4  __attribute__((ext_vector_type(4)));

__device__ __forceinline__ unsigned short f2b(float f) {
  unsigned int u = __builtin_bit_cast(unsigned int, f);
  u = (u + 0x7fffu + ((u >> 16) & 1u)) >> 16;   // RNE
  return (unsigned short)u;
}

__device__ __forceinline__ void async16(const void* g, void* l) {
  // global -> LDS DMA, 16B/lane. LDS dest is wave-uniform base + lane*16.
  __builtin_amdgcn_global_load_lds(
      (__attribute__((address_space(1))) void*)(uintptr_t)g,
      (__attribute__((address_space(3))) void*)l,
      16, 0, 0);
}

__device__ __forceinline__ bf16x8 load_frag(const unsigned short* p) {
  uint4 v = *(const uint4*)p;
  return __builtin_bit_cast(bf16x8, v);
}

// ---------------- cast fp32 -> bf16 ----------------
__global__ __launch_bounds__(256) void cast_kernel(const float* __restrict__ in,
                                                   unsigned short* __restrict__ out,
                                                   int n4) {
  int i = blockIdx.x * blockDim.x + threadIdx.x;
  int stride = gridDim.x * blockDim.x;
  for (; i < n4; i += stride) {
    float4 v = ((const float4*)in)[i];
    ushort4 o;
    o.x = f2b(v.x); o.y = f2b(v.y); o.z = f2b(v.z); o.w = f2b(v.w);
    ((ushort4*)out)[i] = o;
  }
}

// ---------------- router: grid-stride waves, LDS histogram, NO global atomics ----
__global__ __launch_bounds__(256) void router_kernel(const float* __restrict__ x,
                                                     const float* __restrict__ rw,
                                                     unsigned short* __restrict__ xb,
                                                     int* __restrict__ tok_e,
                                                     float* __restrict__ tok_w,
                                                     int* __restrict__ hist) {
  __shared__ float srw[NEXP * HDIM];   // 32 KB: router weights, read 8x per token
  __shared__ int hcnt[NEXP];
  int tid = threadIdx.x;
  for (int i = tid; i < (NEXP * HDIM) / 4; i += 256)
    ((float4*)srw)[i] = ((const float4*)rw)[i];
  if (tid < NEXP) hcnt[tid] = 0;
  __syncthreads();

  int wid = tid >> 6, lane = tid & 63;
  int gwave = blockIdx.x * 4 + wid;
  int nw = RBLK * 4;
  for (int t = gwave; t < NTOK; t += nw) {
    const float* xp = x + (size_t)t * HDIM;
    float xv[16];
#pragma unroll
    for (int j = 0; j < 16; j++) xv[j] = xp[lane + 64 * j];
    // fused cast: write bf16 row while it's in registers
    unsigned short* xbp = xb + (size_t)t * HDIM;
#pragma unroll
    for (int j = 0; j < 16; j++) xbp[lane + 64 * j] = f2b(xv[j]);
    float lg[8];
#pragma unroll
    for (int e = 0; e < 8; e++) {
      const float* wp = srw + e * HDIM;
      float s = 0.f;
#pragma unroll
      for (int j = 0; j < 16; j++) s += xv[j] * wp[lane + 64 * j];
#pragma unroll
      for (int off = 32; off > 0; off >>= 1) s += __shfl_xor(s, off, 64);
      lg[e] = s;
    }
    int e0 = 0; float l0 = lg[0];
#pragma unroll
    for (int e = 1; e < 8; e++) if (lg[e] > l0) { l0 = lg[e]; e0 = e; }
    int e1 = -1; float l1 = -3.0e38f;
#pragma unroll
    for (int e = 0; e < 8; e++) if (e != e0 && lg[e] > l1) { l1 = lg[e]; e1 = e; }
    float w0 = 1.f / (1.f + __expf(l1 - l0));   // == renormalized top-2 softmax
    if (lane == 0) {
      tok_e[t * 2 + 0] = e0; tok_e[t * 2 + 1] = e1;
      tok_w[t * 2 + 0] = w0; tok_w[t * 2 + 1] = 1.f - w0;
      atomicAdd(&hcnt[e0], 1);   // LDS atomic: cheap
      atomicAdd(&hcnt[e1], 1);
    }
  }
  __syncthreads();
  if (tid < NEXP) hist[blockIdx.x * NEXP + tid] = hcnt[tid];  // plain store
}

// ---------------- scan: one wave sums hist[RBLK][8] -> offs ----------------
__global__ void scan_kernel(const int* __restrict__ hist, int* __restrict__ offs) {
  int lane = threadIdx.x & 63;
  int tot[NEXP];
#pragma unroll
  for (int e = 0; e < NEXP; e++) {
    int s = 0;
    for (int b = lane; b < RBLK; b += 64) s += hist[b * NEXP + e];
#pragma unroll
    for (int off = 32; off > 0; off >>= 1) s += __shfl_xor(s, off, 64);
    tot[e] = s;
  }
  if (lane == 0) {
    int s = 0;
#pragma unroll
    for (int e = 0; e < NEXP; e++) { offs[e] = s; s += tot[e]; }
    offs[NEXP] = s;
  }
}

// ---------------- scatter: block-level range reservation ----------------
__global__ __launch_bounds__(256) void scatter_kernel(const int* __restrict__ tok_e,
                                                      const float* __restrict__ tok_w,
                                                      const int* __restrict__ offs,
                                                      int* __restrict__ cursor,
                                                      int* __restrict__ asg_tok,
                                                      float* __restrict__ asg_w) {
  __shared__ int lcnt[NEXP], lbase[NEXP], lpos[NEXP];
  int tid = threadIdx.x;
  if (tid < NEXP) { lcnt[tid] = 0; lpos[tid] = 0; }
  __syncthreads();
  int t = blockIdx.x * 256 + tid;
  int e0 = tok_e[t * 2 + 0], e1 = tok_e[t * 2 + 1];
  float w0 = tok_w[t * 2 + 0], w1 = tok_w[t * 2 + 1];
  atomicAdd(&lcnt[e0], 1);
  atomicAdd(&lcnt[e1], 1);
  __syncthreads();
  if (tid < NEXP) {
    int c = lcnt[tid];
    lbase[tid] = c ? atomicAdd(&cursor[tid], c) : 0;
  }
  __syncthreads();
  int p0 = atomicAdd(&lpos[e0], 1);
  int q0 = offs[e0] + lbase[e0] + p0;
  asg_tok[q0] = t; asg_w[q0] = w0;
  int p1 = atomicAdd(&lpos[e1], 1);
  int q1 = offs[e1] + lbase[e1] + p1;
  asg_tok[q1] = t; asg_w[q1] = w1;
}

// ---------------- GEMM1: hact = silu(X*Wg^T) * (X*Wu^T), grouped, dual-B fused ----------------
// grid = (ichunk/128, 128, NEXP); tile 128x128, BK=32, K=HDIM
// Pipelined (T3 min recipe + T4 + T5): double-buffered LDS (2x24KB = 48KB,
// preserves 2 blocks/CU), raw s_barrier + counted vmcnt(6) so the next
// K-step's global_load_lds stays in flight across the barrier (never drain
// to 0 in the main loop). BK=32 row = 64B: swizzle re-derived -> read col
// quad^((mrow>>1)&3), source col (t&3)^((t>>3)&3): uniform 8 lanes/bank
// group = b128 minimum (conflict-free).
__global__ __launch_bounds__(256, 2) void gemm1_kernel(
    const unsigned short* __restrict__ xb,
    const unsigned short* __restrict__ wg,
    const unsigned short* __restrict__ wu,
    const int* __restrict__ asg_tok,
    const int* __restrict__ offs,
    unsigned short* __restrict__ hact,
    int i0, int ichunk) {
  int nt = blockIdx.x;
  int mt = blockIdx.y;
  int e  = blockIdx.z;
  int base = offs[e];
  int rows = offs[e + 1] - base;
  if (mt * 128 >= rows) return;

  __shared__ __align__(16) unsigned short lA [2][128 * 32];
  __shared__ __align__(16) unsigned short lBg[2][128 * 32];
  __shared__ __align__(16) unsigned short lBu[2][128 * 32];

  int t = threadIdx.x;
  int lane = t & 63, wid = t >> 6;
  int wm = wid & 1, wn = wid >> 1;
  int mrow = lane & 15, quad = lane >> 4;
  int r0   = t >> 2;                               // staging row within 64-row round
  int csrc = (((t & 3) ^ ((t >> 3) & 3)) << 3);    // pre-swizzled source col (shorts)
  int cr   = ((quad ^ ((mrow >> 1) & 3)) << 3);    // swizzled read col (shorts)
  int dst  = t * 8;                                // linear LDS dest (shorts)

  const unsigned short *aP0, *aP1, *gP0, *gP1, *uP0, *uP1;
  {
    int a0 = mt * 128 + r0;      if (a0 >= rows) a0 = rows - 1;
    int a1 = mt * 128 + 64 + r0; if (a1 >= rows) a1 = rows - 1;
    aP0 = xb + (size_t)asg_tok[base + a0] * HDIM + csrc;
    aP1 = xb + (size_t)asg_tok[base + a1] * HDIM + csrc;
    int b0 = i0 + nt * 128 + r0, b1 = b0 + 64;
    gP0 = wg + ((size_t)e * IDIM + b0) * HDIM + csrc;
    gP1 = wg + ((size_t)e * IDIM + b1) * HDIM + csrc;
    uP0 = wu + ((size_t)e * IDIM + b0) * HDIM + csrc;
    uP1 = wu + ((size_t)e * IDIM + b1) * HDIM + csrc;
  }

  f32x4 accg[4][4], accu[4][4];
#pragma unroll
  for (int i = 0; i < 4; i++)
#pragma unroll
    for (int j = 0; j < 4; j++) { accg[i][j] = (f32x4)(0.f); accu[i][j] = (f32x4)(0.f); }

#define STAGE1(B, K) do {                                      \
    async16(aP0 + (K), &lA [B][dst]);                          \
    async16(aP1 + (K), &lA [B][2048 + dst]);                   \
    async16(gP0 + (K), &lBg[B][dst]);                          \
    async16(gP1 + (K), &lBg[B][2048 + dst]);                   \
    async16(uP0 + (K), &lBu[B][dst]);                          \
    async16(uP1 + (K), &lBu[B][2048 + dst]); } while (0)

#define COMPUTE1(B) do {                                                       \
    bf16x8 af[4], bgf[4], buf2[4];                                             \
    _Pragma("unroll")                                                          \
    for (int i = 0; i < 4; i++) {                                              \
      af[i]   = load_frag(&lA [B][(wm * 64 + i * 16 + mrow) * 32 + cr]);       \
      bgf[i]  = load_frag(&lBg[B][(wn * 64 + i * 16 + mrow) * 32 + cr]);       \
      buf2[i] = load_frag(&lBu[B][(wn * 64 + i * 16 + mrow) * 32 + cr]);       \
    }                                                                          \
    __builtin_amdgcn_s_setprio(1);                                             \
    _Pragma("unroll")                                                          \
    for (int mi = 0; mi < 4; mi++)                                             \
      _Pragma("unroll")                                                        \
      for (int ni = 0; ni < 4; ni++) {                                         \
        accg[mi][ni] = __builtin_amdgcn_mfma_f32_16x16x32_bf16(af[mi], bgf[ni],  accg[mi][ni], 0, 0, 0); \
        accu[mi][ni] = __builtin_amdgcn_mfma_f32_16x16x32_bf16(af[mi], buf2[ni], accu[mi][ni], 0, 0, 0); \
      }                                                                        \
    __builtin_amdgcn_s_setprio(0); } while (0)

  STAGE1(0, 0);
  for (int kk = 0; kk < (HDIM / 32) - 1; kk++) {
    int cur = kk & 1;
    STAGE1(cur ^ 1, (kk + 1) * 32);
    asm volatile("s_waitcnt vmcnt(6)" ::: "memory");   // stage(kk) landed; kk+1 in flight
    __builtin_amdgcn_s_barrier();
    COMPUTE1(cur);
    __builtin_amdgcn_sched_barrier(0);                 // pin ds_reads before release
    __builtin_amdgcn_s_barrier();                      // all waves done reading buf[cur]
  }
  asm volatile("s_waitcnt vmcnt(0)" ::: "memory");     // drain final stage
  __builtin_amdgcn_s_barrier();
  COMPUTE1(((HDIM / 32) - 1) & 1);
#undef STAGE1
#undef COMPUTE1

  // epilogue: silu(g)*u -> bf16 (hact is [NASG][ichunk], chunk-local cols)
#pragma unroll
  for (int mi = 0; mi < 4; mi++) {
#pragma unroll
    for (int r = 0; r < 4; r++) {
      int row = mt * 128 + wm * 64 + mi * 16 + quad * 4 + r;
      if (row < rows) {
        size_t rb = (size_t)(base + row) * ichunk + nt * 128 + wn * 64;
#pragma unroll
        for (int ni = 0; ni < 4; ni++) {
          float g = accg[mi][ni][r];
          float u = accu[mi][ni][r];
          float h = g / (1.f + __expf(-g)) * u;
          hact[rb + ni * 16 + mrow] = f2b(h);
        }
      }
    }
  }
}

// ---------------- GEMM2: out += w * (hact * Wd^T), grouped ----------------
// grid = (HDIM/256, 128, NEXP); tile 128x256, BK=32, K=ichunk — same
// pipelined structure as gemm1 (dbuf 48KB, counted vmcnt, raw barriers).
__global__ __launch_bounds__(256, 2) void gemm2_kernel(
    const unsigned short* __restrict__ hact,
    const unsigned short* __restrict__ wd,
    const int* __restrict__ asg_tok,
    const float* __restrict__ asg_w,
    const int* __restrict__ offs,
    float* __restrict__ out,
    int i0, int ichunk) {
  int nt = blockIdx.x;
  int mt = blockIdx.y;
  int e  = blockIdx.z;
  int base = offs[e];
  int rows = offs[e + 1] - base;
  if (mt * 128 >= rows) return;

  __shared__ __align__(16) unsigned short lA[2][128 * 32];   // 16 KB
  __shared__ __align__(16) unsigned short lB[2][256 * 32];   // 32 KB

  int t = threadIdx.x;
  int lane = t & 63, wid = t >> 6;
  int wm = wid & 1, wn = wid >> 1;          // 2x2 waves; each wave: 64 rows x 128 cols
  int mrow = lane & 15, quad = lane >> 4;
  int r0   = t >> 2;
  int csrc = (((t & 3) ^ ((t >> 3) & 3)) << 3);
  int cr   = ((quad ^ ((mrow >> 1) & 3)) << 3);
  int dst  = t * 8;

  const unsigned short *aP0, *aP1, *bP0, *bP1, *bP2, *bP3;
  {
    int a0 = mt * 128 + r0;      if (a0 >= rows) a0 = rows - 1;
    int a1 = mt * 128 + 64 + r0; if (a1 >= rows) a1 = rows - 1;
    aP0 = hact + (size_t)(base + a0) * ichunk + csrc;
    aP1 = hact + (size_t)(base + a1) * ichunk + csrc;
    int b0 = nt * 256 + r0;
    bP0 = wd + ((size_t)e * HDIM + b0)       * IDIM + i0 + csrc;
    bP1 = wd + ((size_t)e * HDIM + b0 + 64)  * IDIM + i0 + csrc;
    bP2 = wd + ((size_t)e * HDIM + b0 + 128) * IDIM + i0 + csrc;
    bP3 = wd + ((size_t)e * HDIM + b0 + 192) * IDIM + i0 + csrc;
  }

  f32x4 acc[4][8];
#pragma unroll
  for (int i = 0; i < 4; i++)
#pragma unroll
    for (int j = 0; j < 8; j++) acc[i][j] = (f32x4)(0.f);

#define STAGE2(B, K) do {                                      \
    async16(aP0 + (K), &lA[B][dst]);                           \
    async16(aP1 + (K), &lA[B][2048 + dst]);                    \
    async16(bP0 + (K), &lB[B][dst]);                           \
    async16(bP1 + (K), &lB[B][2048 + dst]);                    \
    async16(bP2 + (K), &lB[B][4096 + dst]);                    \
    async16(bP3 + (K), &lB[B][6144 + dst]); } while (0)

#define COMPUTE2(B) do {                                                       \
    bf16x8 af[4], bf[8];                                                       \
    _Pragma("unroll")                                                          \
    for (int i = 0; i < 4; i++)                                                \
      af[i] = load_frag(&lA[B][(wm * 64 + i * 16 + mrow) * 32 + cr]);          \
    _Pragma("unroll")                                                          \
    for (int i = 0; i < 8; i++)                                                \
      bf[i] = load_frag(&lB[B][(wn * 128 + i * 16 + mrow) * 32 + cr]);         \
    __builtin_amdgcn_s_setprio(1);                                             \
    _Pragma("unroll")                                                          \
    for (int mi = 0; mi < 4; mi++)                                             \
      _Pragma("unroll")                                                        \
      for (int ni = 0; ni < 8; ni++)                                           \
        acc[mi][ni] = __builtin_amdgcn_mfma_f32_16x16x32_bf16(af[mi], bf[ni], acc[mi][ni], 0, 0, 0); \
    __builtin_amdgcn_s_setprio(0); } while (0)

  int NIT = ichunk / 32;
  STAGE2(0, 0);
  for (int kk = 0; kk < NIT - 1; kk++) {
    int cur = kk & 1;
    STAGE2(cur ^ 1, (kk + 1) * 32);
    asm volatile("s_waitcnt vmcnt(6)" ::: "memory");
    __builtin_amdgcn_s_barrier();
    COMPUTE2(cur);
    __builtin_amdgcn_sched_barrier(0);
    __builtin_amdgcn_s_barrier();
  }
  asm volatile("s_waitcnt vmcnt(0)" ::: "memory");
  __builtin_amdgcn_s_barrier();
  COMPUTE2((NIT - 1) & 1);
#undef STAGE2
#undef COMPUTE2

  // epilogue: scale by routing weight, atomic-accumulate into out
#pragma unroll
  for (int mi = 0; mi < 4; mi++) {
#pragma unroll
    for (int r = 0; r < 4; r++) {
      int row = mt * 128 + wm * 64 + mi * 16 + quad * 4 + r;
      if (row < rows) {
        int ar = base + row;
        int tok = asg_tok[ar];
        float w = asg_w[ar];
        float* op = out + (size_t)tok * HDIM + nt * 256 + wn * 128;
#pragma unroll
        for (int ni = 0; ni < 8; ni++)
          atomicAdd(&op[ni * 16 + mrow], w * acc[mi][ni][r]);
      }
    }
  }
}

// ---------------- launch ----------------
extern "C" void kernel_launch(void* const* d_in, const int* in_sizes, int n_in,
                              void* d_out, int out_size, void* d_ws, size_t ws_size,
                              hipStream_t stream) {
  const float* x  = (const float*)d_in[0];
  const float* rw = (const float*)d_in[1];
  const float* gw = (const float*)d_in[2];
  const float* uw = (const float*)d_in[3];
  const float* dw = (const float*)d_in[4];
  float* out = (float*)d_out;
  char* ws = (char*)d_ws;

  // ---- workspace layout (unchanged footprint: 235,405,440 B on primary path) ----
  unsigned short* wg = (unsigned short*)ws;
  unsigned short* wu = wg + (size_t)NEXP * IDIM * HDIM;
  unsigned short* wd = wu + (size_t)NEXP * IDIM * HDIM;
  char* p = ws + 3ull * NEXP * IDIM * HDIM * 2;
  int*   asg_tok = (int*)p;            p += (size_t)NASG * 4;
  float* asg_w   = (float*)p;          p += (size_t)NASG * 4;
  int*   tok_e   = (int*)p;            p += (size_t)NASG * 4;
  float* tok_w   = (float*)p;          p += (size_t)NASG * 4;
  int*   meta    = (int*)p;            p += 128;
  int* cursor = meta;          // 8
  int* offs   = meta + 8;      // 9

  // hist[RBLK][8] lives in the upper half of d_out (dead until the pre-gemm2
  // memset; scan consumes it long before that).
  int* hist = (int*)((char*)d_out + (40ull << 20));

  int ichunk; bool xb_in_out;
  if      (ws_size >= 235405440ull) { ichunk = 2048; xb_in_out = true;  }
  else if (ws_size >= 201851008ull) { ichunk = 1024; xb_in_out = false; }
  else if (ws_size >= 168296576ull) { ichunk = 512;  xb_in_out = false; }
  else                              { ichunk = 256;  xb_in_out = false; }

  unsigned short* xb;
  unsigned short* hact;
  if (xb_in_out) {
    xb   = (unsigned short*)d_out;       // first 33.5 MB of the 67 MB output
    hact = (unsigned short*)p;           // 134.2 MB
  } else {
    xb   = (unsigned short*)p;
    hact = (unsigned short*)(p + (size_t)NTOK * HDIM * 2);
  }

  hipMemsetAsync(meta, 0, 64, stream);   // cursor

  // fp32 -> bf16 weight casts (x cast fused into router)
  cast_kernel<<<4096, 256, 0, stream>>>(gw, wg, (NEXP * IDIM * HDIM) / 4);
  cast_kernel<<<4096, 256, 0, stream>>>(uw, wu, (NEXP * IDIM * HDIM) / 4);
  cast_kernel<<<4096, 256, 0, stream>>>(dw, wd, (NEXP * HDIM * IDIM) / 4);

  router_kernel<<<RBLK, 256, 0, stream>>>(x, rw, xb, tok_e, tok_w, hist);
  scan_kernel<<<1, 64, 0, stream>>>(hist, offs);
  scatter_kernel<<<NTOK / 256, 256, 0, stream>>>(tok_e, tok_w, offs, cursor, asg_tok, asg_w);

  if (xb_in_out) {
    gemm1_kernel<<<dim3(16, 128, NEXP), 256, 0, stream>>>(xb, wg, wu, asg_tok, offs, hact, 0, 2048);
    // xb (in d_out) is dead now; zero d_out for atomic accumulation
    hipMemsetAsync(d_out, 0, (size_t)out_size * sizeof(float), stream);
    gemm2_kernel<<<dim3(HDIM / 256, 128, NEXP), 256, 0, stream>>>(hact, wd, asg_tok, asg_w, offs, out, 0, 2048);
  } else {
    hipMemsetAsync(d_out, 0, (size_t)out_size * sizeof(float), stream);
    for (int i0 = 0; i0 < IDIM; i0 += ichunk) {
      gemm1_kernel<<<dim3(ichunk / 128, 128, NEXP), 256, 0, stream>>>(xb, wg, wu, asg_tok, offs, hact, i0, ichunk);
      gemm2_kernel<<<dim3(HDIM / 256, 128, NEXP), 256, 0, stream>>>(hact, wd, asg_tok, asg_w, offs, out, i0, ichunk);
    }
  }
}

// Round 5
// 839.804 us; speedup vs baseline: 1.0782x; 1.0782x over previous
//
#include <hip/hip_runtime.h>
#include <stdint.h>

// ---------------- problem constants ----------------
#define NTOK   16384      // B*S
#define HDIM   1024
#define IDIM   2048
#define NEXP   8
#define NASG   (NTOK*2)   // top-2 assignments
#define RBLK   512        // router grid blocks (2 per CU)

typedef __bf16 bf16x8 __attribute__((ext_vector_type(8)));
typedef float  f32x4  __attribute__((ext_vector_type(4)));

__device__ __forceinline__ unsigned short f2b(float f) {
  unsigned int u = __builtin_bit_cast(unsigned int, f);
  u = (u + 0x7fffu + ((u >> 16) & 1u)) >> 16;   // RNE
  return (unsigned short)u;
}

__device__ __forceinline__ void async16(const void* g, void* l) {
  // global -> LDS DMA, 16B/lane. LDS dest is wave-uniform base + lane*16.
  __builtin_amdgcn_global_load_lds(
      (__attribute__((address_space(1))) void*)(uintptr_t)g,
      (__attribute__((address_space(3))) void*)l,
      16, 0, 0);
}

__device__ __forceinline__ bf16x8 load_frag(const unsigned short* p) {
  uint4 v = *(const uint4*)p;
  return __builtin_bit_cast(bf16x8, v);
}

// ---------------- cast fp32 -> bf16 ----------------
__global__ __launch_bounds__(256) void cast_kernel(const float* __restrict__ in,
                                                   unsigned short* __restrict__ out,
                                                   int n4) {
  int i = blockIdx.x * blockDim.x + threadIdx.x;
  int stride = gridDim.x * blockDim.x;
  for (; i < n4; i += stride) {
    float4 v = ((const float4*)in)[i];
    ushort4 o;
    o.x = f2b(v.x); o.y = f2b(v.y); o.z = f2b(v.z); o.w = f2b(v.w);
    ((ushort4*)out)[i] = o;
  }
}

// ---------------- router: grid-stride waves, LDS histogram, NO global atomics ----
__global__ __launch_bounds__(256) void router_kernel(const float* __restrict__ x,
                                                     const float* __restrict__ rw,
                                                     unsigned short* __restrict__ xb,
                                                     int* __restrict__ tok_e,
                                                     float* __restrict__ tok_w,
                                                     int* __restrict__ hist) {
  __shared__ float srw[NEXP * HDIM];   // 32 KB: router weights, read 8x per token
  __shared__ int hcnt[NEXP];
  int tid = threadIdx.x;
  for (int i = tid; i < (NEXP * HDIM) / 4; i += 256)
    ((float4*)srw)[i] = ((const float4*)rw)[i];
  if (tid < NEXP) hcnt[tid] = 0;
  __syncthreads();

  int wid = tid >> 6, lane = tid & 63;
  int gwave = blockIdx.x * 4 + wid;
  int nw = RBLK * 4;
  for (int t = gwave; t < NTOK; t += nw) {
    const float* xp = x + (size_t)t * HDIM;
    float xv[16];
#pragma unroll
    for (int j = 0; j < 16; j++) xv[j] = xp[lane + 64 * j];
    // fused cast: write bf16 row while it's in registers
    unsigned short* xbp = xb + (size_t)t * HDIM;
#pragma unroll
    for (int j = 0; j < 16; j++) xbp[lane + 64 * j] = f2b(xv[j]);
    float lg[8];
#pragma unroll
    for (int e = 0; e < 8; e++) {
      const float* wp = srw + e * HDIM;
      float s = 0.f;
#pragma unroll
      for (int j = 0; j < 16; j++) s += xv[j] * wp[lane + 64 * j];
#pragma unroll
      for (int off = 32; off > 0; off >>= 1) s += __shfl_xor(s, off, 64);
      lg[e] = s;
    }
    int e0 = 0; float l0 = lg[0];
#pragma unroll
    for (int e = 1; e < 8; e++) if (lg[e] > l0) { l0 = lg[e]; e0 = e; }
    int e1 = -1; float l1 = -3.0e38f;
#pragma unroll
    for (int e = 0; e < 8; e++) if (e != e0 && lg[e] > l1) { l1 = lg[e]; e1 = e; }
    float w0 = 1.f / (1.f + __expf(l1 - l0));   // == renormalized top-2 softmax
    if (lane == 0) {
      tok_e[t * 2 + 0] = e0; tok_e[t * 2 + 1] = e1;
      tok_w[t * 2 + 0] = w0; tok_w[t * 2 + 1] = 1.f - w0;
      atomicAdd(&hcnt[e0], 1);   // LDS atomic: cheap
      atomicAdd(&hcnt[e1], 1);
    }
  }
  __syncthreads();
  if (tid < NEXP) hist[blockIdx.x * NEXP + tid] = hcnt[tid];  // plain store
}

// ---------------- scan: one wave sums hist[RBLK][8] -> offs ----------------
__global__ void scan_kernel(const int* __restrict__ hist, int* __restrict__ offs) {
  int lane = threadIdx.x & 63;
  int tot[NEXP];
#pragma unroll
  for (int e = 0; e < NEXP; e++) {
    int s = 0;
    for (int b = lane; b < RBLK; b += 64) s += hist[b * NEXP + e];
#pragma unroll
    for (int off = 32; off > 0; off >>= 1) s += __shfl_xor(s, off, 64);
    tot[e] = s;
  }
  if (lane == 0) {
    int s = 0;
#pragma unroll
    for (int e = 0; e < NEXP; e++) { offs[e] = s; s += tot[e]; }
    offs[NEXP] = s;
  }
}

// ---------------- scatter: block-level range reservation ----------------
__global__ __launch_bounds__(256) void scatter_kernel(const int* __restrict__ tok_e,
                                                      const float* __restrict__ tok_w,
                                                      const int* __restrict__ offs,
                                                      int* __restrict__ cursor,
                                                      int* __restrict__ asg_tok,
                                                      float* __restrict__ asg_w) {
  __shared__ int lcnt[NEXP], lbase[NEXP], lpos[NEXP];
  int tid = threadIdx.x;
  if (tid < NEXP) { lcnt[tid] = 0; lpos[tid] = 0; }
  __syncthreads();
  int t = blockIdx.x * 256 + tid;
  int e0 = tok_e[t * 2 + 0], e1 = tok_e[t * 2 + 1];
  float w0 = tok_w[t * 2 + 0], w1 = tok_w[t * 2 + 1];
  atomicAdd(&lcnt[e0], 1);
  atomicAdd(&lcnt[e1], 1);
  __syncthreads();
  if (tid < NEXP) {
    int c = lcnt[tid];
    lbase[tid] = c ? atomicAdd(&cursor[tid], c) : 0;
  }
  __syncthreads();
  int p0 = atomicAdd(&lpos[e0], 1);
  int q0 = offs[e0] + lbase[e0] + p0;
  asg_tok[q0] = t; asg_w[q0] = w0;
  int p1 = atomicAdd(&lpos[e1], 1);
  int q1 = offs[e1] + lbase[e1] + p1;
  asg_tok[q1] = t; asg_w[q1] = w1;
}

// ---------------- GEMM1: hact = silu(X*Wg^T) * (X*Wu^T) ----------------
// 256x128 tile, 512 thr (8 waves 4Mx2N, wave tile 64x64), BK=64, K=HDIM.
// Double-buffered LDS = 128 KB (1 block/CU). Schedule: stage(t+1) is issued
// INSIDE tile t's compute (interleaved between MFMA clusters); at tile t+1
// entry, vmcnt(0) waits only on loads issued a full compute-block (~2.5k cyc)
// earlier -> near-free. Round-4 lesson: keep BK=64 (barrier count), overlap
// stage with compute instead of shrinking K-step. XOR swizzle identical to
// the round-2-verified BK=64 math (measured 0 conflicts).
__global__ __launch_bounds__(512, 1) void gemm1_kernel(
    const unsigned short* __restrict__ xb,
    const unsigned short* __restrict__ wg,
    const unsigned short* __restrict__ wu,
    const int* __restrict__ asg_tok,
    const int* __restrict__ offs,
    unsigned short* __restrict__ hact,
    int i0, int ichunk) {
  int nt = blockIdx.x;
  int mt = blockIdx.y;
  int e  = blockIdx.z;
  int base = offs[e];
  int rows = offs[e + 1] - base;
  if (mt * 256 >= rows) return;

  __shared__ __align__(16) unsigned short lA [2][256 * 64];   // 64 KB
  __shared__ __align__(16) unsigned short lBg[2][128 * 64];   // 32 KB
  __shared__ __align__(16) unsigned short lBu[2][128 * 64];   // 32 KB

  int t = threadIdx.x;                  // 0..511
  int lane = t & 63, wid = t >> 6;      // 8 waves
  int wm = wid & 3, wn = wid >> 2;      // 4M x 2N
  int mrow = lane & 15, quad = lane >> 4;
  int row8 = t >> 3;                    // 0..63 staging row within 64-row round
  int csrc = (((t & 7) ^ (row8 & 7)) << 3);   // pre-swizzled source col (shorts)
  int sw   = mrow & 7;                        // read-side swizzle key
  int dst  = t * 8;                           // linear LDS dest (shorts)

  const unsigned short *aP[4], *gP[2], *uP[2];
#pragma unroll
  for (int r = 0; r < 4; r++) {
    int arow = mt * 256 + r * 64 + row8;
    if (arow >= rows) arow = rows - 1;
    aP[r] = xb + (size_t)asg_tok[base + arow] * HDIM + csrc;
  }
#pragma unroll
  for (int r = 0; r < 2; r++) {
    int brow = i0 + nt * 128 + r * 64 + row8;
    gP[r] = wg + ((size_t)e * IDIM + brow) * HDIM + csrc;
    uP[r] = wu + ((size_t)e * IDIM + brow) * HDIM + csrc;
  }

  f32x4 accg[4][4], accu[4][4];
#pragma unroll
  for (int i = 0; i < 4; i++)
#pragma unroll
    for (int j = 0; j < 4; j++) { accg[i][j] = (f32x4)(0.f); accu[i][j] = (f32x4)(0.f); }

#define STG1A(B, K) do {                                   \
    async16(aP[0] + (K), &lA[B][dst]);                     \
    async16(aP[1] + (K), &lA[B][4096 + dst]);              \
    async16(aP[2] + (K), &lA[B][8192 + dst]);              \
    async16(aP[3] + (K), &lA[B][12288 + dst]); } while (0)
#define STG1B(B, K) do {                                   \
    async16(gP[0] + (K), &lBg[B][dst]);                    \
    async16(gP[1] + (K), &lBg[B][4096 + dst]);             \
    async16(uP[0] + (K), &lBu[B][dst]);                    \
    async16(uP[1] + (K), &lBu[B][4096 + dst]); } while (0)

  STG1A(0, 0); STG1B(0, 0);

  for (int kt = 0; kt < HDIM / 64; kt++) {
    int cur = kt & 1;
    asm volatile("s_waitcnt vmcnt(0)" ::: "memory");  // tile kt staged (issued 1 block ago)
    __builtin_amdgcn_s_barrier();
    int nk = (kt + 1) * 64;
    bool pf = (kt + 1) < (HDIM / 64);
#pragma unroll
    for (int kh = 0; kh < 2; kh++) {
      int ko = ((((kh << 2) | quad) ^ sw) << 3);
      bf16x8 af[4], bgf[4];
#pragma unroll
      for (int i = 0; i < 4; i++) {
        af[i]  = load_frag(&lA [cur][(wm * 64 + i * 16 + mrow) * 64 + ko]);
        bgf[i] = load_frag(&lBg[cur][(wn * 64 + i * 16 + mrow) * 64 + ko]);
      }
      if (pf) { if (kh == 0) STG1A(cur ^ 1, nk); else STG1B(cur ^ 1, nk); }
      __builtin_amdgcn_s_setprio(1);
#pragma unroll
      for (int mi = 0; mi < 4; mi++)
#pragma unroll
        for (int ni = 0; ni < 4; ni++)
          accg[mi][ni] = __builtin_amdgcn_mfma_f32_16x16x32_bf16(af[mi], bgf[ni], accg[mi][ni], 0, 0, 0);
      __builtin_amdgcn_s_setprio(0);
      bf16x8 buf2[4];
#pragma unroll
      for (int i = 0; i < 4; i++)
        buf2[i] = load_frag(&lBu[cur][(wn * 64 + i * 16 + mrow) * 64 + ko]);
      __builtin_amdgcn_s_setprio(1);
#pragma unroll
      for (int mi = 0; mi < 4; mi++)
#pragma unroll
        for (int ni = 0; ni < 4; ni++)
          accu[mi][ni] = __builtin_amdgcn_mfma_f32_16x16x32_bf16(af[mi], buf2[ni], accu[mi][ni], 0, 0, 0);
      __builtin_amdgcn_s_setprio(0);
    }
    __builtin_amdgcn_sched_barrier(0);
    __builtin_amdgcn_s_barrier();     // all waves done reading buf[cur]
  }
#undef STG1A
#undef STG1B

  // epilogue: silu(g)*u -> bf16 (hact is [NASG][ichunk], chunk-local cols)
#pragma unroll
  for (int mi = 0; mi < 4; mi++) {
#pragma unroll
    for (int r = 0; r < 4; r++) {
      int row = mt * 256 + wm * 64 + mi * 16 + quad * 4 + r;
      if (row < rows) {
        size_t rb = (size_t)(base + row) * ichunk + nt * 128 + wn * 64;
#pragma unroll
        for (int ni = 0; ni < 4; ni++) {
          float g = accg[mi][ni][r];
          float u = accu[mi][ni][r];
          float h = g / (1.f + __expf(-g)) * u;
          hact[rb + ni * 16 + mrow] = f2b(h);
        }
      }
    }
  }
}

// ---------------- GEMM2: out += w * (hact * Wd^T), grouped ----------------
// 256x256 tile, 512 thr (8 waves 2Mx4N, wave tile 128x64 -> 43.7 FLOP per
// LDS byte, fixing the old 32.8), BK=64, K=ichunk. Same pipelined schedule
// as gemm1; dbuf LDS = 128 KB.
__global__ __launch_bounds__(512, 1) void gemm2_kernel(
    const unsigned short* __restrict__ hact,
    const unsigned short* __restrict__ wd,
    const int* __restrict__ asg_tok,
    const float* __restrict__ asg_w,
    const int* __restrict__ offs,
    float* __restrict__ out,
    int i0, int ichunk) {
  int nt = blockIdx.x;
  int mt = blockIdx.y;
  int e  = blockIdx.z;
  int base = offs[e];
  int rows = offs[e + 1] - base;
  if (mt * 256 >= rows) return;

  __shared__ __align__(16) unsigned short lA[2][256 * 64];   // 64 KB
  __shared__ __align__(16) unsigned short lB[2][256 * 64];   // 64 KB

  int t = threadIdx.x;
  int lane = t & 63, wid = t >> 6;
  int wm = wid & 1, wn = wid >> 1;      // 2M x 4N; wave tile 128 x 64
  int mrow = lane & 15, quad = lane >> 4;
  int row8 = t >> 3;
  int csrc = (((t & 7) ^ (row8 & 7)) << 3);
  int sw   = mrow & 7;
  int dst  = t * 8;

  const unsigned short *aP[4], *bP[4];
#pragma unroll
  for (int r = 0; r < 4; r++) {
    int arow = mt * 256 + r * 64 + row8;
    if (arow >= rows) arow = rows - 1;
    aP[r] = hact + (size_t)(base + arow) * ichunk + csrc;
    int brow = nt * 256 + r * 64 + row8;
    bP[r] = wd + ((size_t)e * HDIM + brow) * IDIM + i0 + csrc;
  }

  f32x4 acc[8][4];
#pragma unroll
  for (int i = 0; i < 8; i++)
#pragma unroll
    for (int j = 0; j < 4; j++) acc[i][j] = (f32x4)(0.f);

#define STG2A(B, K) do {                                   \
    async16(aP[0] + (K), &lA[B][dst]);                     \
    async16(aP[1] + (K), &lA[B][4096 + dst]);              \
    async16(aP[2] + (K), &lA[B][8192 + dst]);              \
    async16(aP[3] + (K), &lA[B][12288 + dst]); } while (0)
#define STG2B(B, K) do {                                   \
    async16(bP[0] + (K), &lB[B][dst]);                     \
    async16(bP[1] + (K), &lB[B][4096 + dst]);              \
    async16(bP[2] + (K), &lB[B][8192 + dst]);              \
    async16(bP[3] + (K), &lB[B][12288 + dst]); } while (0)

  STG2A(0, 0); STG2B(0, 0);

  int NT2 = ichunk / 64;
  for (int kt = 0; kt < NT2; kt++) {
    int cur = kt & 1;
    asm volatile("s_waitcnt vmcnt(0)" ::: "memory");
    __builtin_amdgcn_s_barrier();
    int nk = (kt + 1) * 64;
    bool pf = (kt + 1) < NT2;
#pragma unroll
    for (int kh = 0; kh < 2; kh++) {
      int ko = ((((kh << 2) | quad) ^ sw) << 3);
      bf16x8 af[8], bf[4];
#pragma unroll
      for (int i = 0; i < 8; i++)
        af[i] = load_frag(&lA[cur][(wm * 128 + i * 16 + mrow) * 64 + ko]);
#pragma unroll
      for (int i = 0; i < 4; i++)
        bf[i] = load_frag(&lB[cur][(wn * 64 + i * 16 + mrow) * 64 + ko]);
      if (pf) { if (kh == 0) STG2A(cur ^ 1, nk); else STG2B(cur ^ 1, nk); }
      __builtin_amdgcn_s_setprio(1);
#pragma unroll
      for (int mi = 0; mi < 8; mi++)
#pragma unroll
        for (int ni = 0; ni < 4; ni++)
          acc[mi][ni] = __builtin_amdgcn_mfma_f32_16x16x32_bf16(af[mi], bf[ni], acc[mi][ni], 0, 0, 0);
      __builtin_amdgcn_s_setprio(0);
    }
    __builtin_amdgcn_sched_barrier(0);
    __builtin_amdgcn_s_barrier();
  }
#undef STG2A
#undef STG2B

  // epilogue: scale by routing weight, atomic-accumulate into out
#pragma unroll
  for (int mi = 0; mi < 8; mi++) {
#pragma unroll
    for (int r = 0; r < 4; r++) {
      int row = mt * 256 + wm * 128 + mi * 16 + quad * 4 + r;
      if (row < rows) {
        int ar = base + row;
        int tok = asg_tok[ar];
        float w = asg_w[ar];
        float* op = out + (size_t)tok * HDIM + nt * 256 + wn * 64;
#pragma unroll
        for (int ni = 0; ni < 4; ni++)
          atomicAdd(&op[ni * 16 + mrow], w * acc[mi][ni][r]);
      }
    }
  }
}

// ---------------- launch ----------------
extern "C" void kernel_launch(void* const* d_in, const int* in_sizes, int n_in,
                              void* d_out, int out_size, void* d_ws, size_t ws_size,
                              hipStream_t stream) {
  const float* x  = (const float*)d_in[0];
  const float* rw = (const float*)d_in[1];
  const float* gw = (const float*)d_in[2];
  const float* uw = (const float*)d_in[3];
  const float* dw = (const float*)d_in[4];
  float* out = (float*)d_out;
  char* ws = (char*)d_ws;

  // ---- workspace layout (unchanged footprint: 235,405,440 B on primary path) ----
  unsigned short* wg = (unsigned short*)ws;
  unsigned short* wu = wg + (size_t)NEXP * IDIM * HDIM;
  unsigned short* wd = wu + (size_t)NEXP * IDIM * HDIM;
  char* p = ws + 3ull * NEXP * IDIM * HDIM * 2;
  int*   asg_tok = (int*)p;            p += (size_t)NASG * 4;
  float* asg_w   = (float*)p;          p += (size_t)NASG * 4;
  int*   tok_e   = (int*)p;            p += (size_t)NASG * 4;
  float* tok_w   = (float*)p;          p += (size_t)NASG * 4;
  int*   meta    = (int*)p;            p += 128;
  int* cursor = meta;          // 8
  int* offs   = meta + 8;      // 9

  // hist[RBLK][8] lives in the upper half of d_out (dead until the pre-gemm2
  // memset; scan consumes it long before that).
  int* hist = (int*)((char*)d_out + (40ull << 20));

  int ichunk; bool xb_in_out;
  if      (ws_size >= 235405440ull) { ichunk = 2048; xb_in_out = true;  }
  else if (ws_size >= 201851008ull) { ichunk = 1024; xb_in_out = false; }
  else if (ws_size >= 168296576ull) { ichunk = 512;  xb_in_out = false; }
  else                              { ichunk = 256;  xb_in_out = false; }

  unsigned short* xb;
  unsigned short* hact;
  if (xb_in_out) {
    xb   = (unsigned short*)d_out;       // first 33.5 MB of the 67 MB output
    hact = (unsigned short*)p;           // 134.2 MB
  } else {
    xb   = (unsigned short*)p;
    hact = (unsigned short*)(p + (size_t)NTOK * HDIM * 2);
  }

  hipMemsetAsync(meta, 0, 64, stream);   // cursor

  // fp32 -> bf16 weight casts (x cast fused into router)
  cast_kernel<<<4096, 256, 0, stream>>>(gw, wg, (NEXP * IDIM * HDIM) / 4);
  cast_kernel<<<4096, 256, 0, stream>>>(uw, wu, (NEXP * IDIM * HDIM) / 4);
  cast_kernel<<<4096, 256, 0, stream>>>(dw, wd, (NEXP * HDIM * IDIM) / 4);

  router_kernel<<<RBLK, 256, 0, stream>>>(x, rw, xb, tok_e, tok_w, hist);
  scan_kernel<<<1, 64, 0, stream>>>(hist, offs);
  scatter_kernel<<<NTOK / 256, 256, 0, stream>>>(tok_e, tok_w, offs, cursor, asg_tok, asg_w);

  if (xb_in_out) {
    gemm1_kernel<<<dim3(16, 128, NEXP), 512, 0, stream>>>(xb, wg, wu, asg_tok, offs, hact, 0, 2048);
    // xb (in d_out) is dead now; zero d_out for atomic accumulation
    hipMemsetAsync(d_out, 0, (size_t)out_size * sizeof(float), stream);
    gemm2_kernel<<<dim3(HDIM / 256, 128, NEXP), 512, 0, stream>>>(hact, wd, asg_tok, asg_w, offs, out, 0, 2048);
  } else {
    hipMemsetAsync(d_out, 0, (size_t)out_size * sizeof(float), stream);
    for (int i0 = 0; i0 < IDIM; i0 += ichunk) {
      gemm1_kernel<<<dim3(ichunk / 128, 128, NEXP), 512, 0, stream>>>(xb, wg, wu, asg_tok, offs, hact, i0, ichunk);
      gemm2_kernel<<<dim3(HDIM / 256, 128, NEXP), 512, 0, stream>>>(hact, wd, asg_tok, asg_w, offs, out, i0, ichunk);
    }
  }
}